// Round 1
// baseline (273.585 us; speedup 1.0000x reference)
//
#include <hip/hip_runtime.h>
#include <stdint.h>

// DifferentiableSkeletonize on (2,1,256,256,256) binary fp32 mask.
// dilated = avgpool3(avgpool3(x)) = separable per-axis double-box:
//   interior kernel [1,2,3,2,1]/9 (zero-extended), boundary rows (i=0, i=255)
//   get the zero-extended triangular MINUS one extra center tap ([2,2,1]/9).
// n = integer numerator in [0,729]; dilated = n/729.
// out = 1 - rint(clip(0.3*x + 3.5*(sigmoid((x - n/729 - 0.5)/0.3) + x - n/729), 0, 1))

#define SLABS 512      // b*h (or b*w) slabs
#define CH 32          // outputs per wave along the marching axis
#define NCHUNK 8       // 256 / CH
#define WAVES (SLABS * NCHUNK)   // 4096
#define BLOCKS (WAVES / 4)       // 1024 blocks of 256 threads

// Pack one d-row (lane ln owns floats d4..d4+3) into 4 bytes:
// byte j = n_d(d4+j) (<=9) | (x(d4+j) ? 0x80 : 0)
__device__ __forceinline__ uint32_t row_pack(const float4 v, const int ln) {
    uint32_t b = (v.x > 0.5f ? 0x1u : 0u)
               | (v.y > 0.5f ? 0x100u : 0u)
               | (v.z > 0.5f ? 0x10000u : 0u)
               | (v.w > 0.5f ? 0x1000000u : 0u);
    uint32_t up = (uint32_t)__shfl_up((int)b, 1);
    uint32_t dn = (uint32_t)__shfl_down((int)b, 1);
    if (ln == 0)  up = 0u;   // x[-1], x[-2] are zero
    if (ln == 63) dn = 0u;   // x[256], x[257] are zero
    // W bytes 0..7 = x[d4-2 .. d4+5]
    uint64_t W = (uint64_t)(up >> 16) | ((uint64_t)b << 16)
               | ((uint64_t)(dn & 0xffffu) << 48);
    // byte j of S = W_j + 2W_{j+1} + 3W_{j+2} + 2W_{j+3} + W_{j+4}  (max 9, no carries)
    uint64_t S = W + ((W >> 8) << 1) + (W >> 16) * 3u + ((W >> 24) << 1) + (W >> 32);
    uint32_t n = (uint32_t)S;
    // d-axis boundary correction: subtract one center tap at d==0 / d==255
    if (ln == 0)  n -= (b & 0xffu);
    if (ln == 63) n -= (b & 0xff000000u);
    return n | (b << 7);   // x-bit into bit7 of each byte (values 0/1 -> 0/0x80)
}

// K1: fused d-axis + w-axis filtering. One wave per (slab, w-chunk).
// Writes u8[byte j] = n_dw (<=81) | x-bit.
__global__ __launch_bounds__(256) void skel_k1(const float* __restrict__ x,
                                               uint32_t* __restrict__ ws) {
    const int ln    = threadIdx.x & 63;
    const int wid   = (blockIdx.x << 2) | (threadIdx.x >> 6);
    const int chunk = wid & (NCHUNK - 1);
    const int slab  = wid >> 3;                 // bi*256 + hi
    const int w0    = chunk * CH;
    const float4* xs = (const float4*)(x + (size_t)slab * 65536);
    uint32_t* os = ws + (size_t)slab * 16384;

    auto loadrow = [&](int wi) -> uint32_t {
        if (wi < 0 || wi > 255) return 0u;      // wave-uniform branch
        return row_pack(xs[wi * 64 + ln], ln);
    };
    uint32_t r0 = loadrow(w0 - 2), r1 = loadrow(w0 - 1), r2 = loadrow(w0),
             r3 = loadrow(w0 + 1), r4 = loadrow(w0 + 2);
    for (int w = w0; w < w0 + CH; ++w) {
        uint32_t rn = loadrow(w + 3);           // prefetch next row
        uint32_t n0 = r0 & 0x7f7f7f7fu, n1 = r1 & 0x7f7f7f7fu, n2 = r2 & 0x7f7f7f7fu,
                 n3 = r3 & 0x7f7f7f7fu, n4 = r4 & 0x7f7f7f7fu;
        uint32_t s = n0 + (n1 << 1) + n2 * 3u + (n3 << 1) + n4;  // bytes <= 81
        if (w == 0 || w == 255) s -= n2;        // w-axis boundary correction
        s |= (r2 & 0x80808080u);                // carry center-x bit
        os[w * 64 + ln] = s;
        r0 = r1; r1 = r2; r2 = r3; r3 = r4; r4 = rn;
    }
}

__device__ __forceinline__ float skel_pointwise(uint32_t n, uint32_t xi) {
    float xf   = (float)xi;
    float d    = (float)n * (1.0f / 729.0f);
    float diff = xf - d;
    float t    = (diff - 0.5f) * (1.0f / 0.3f);
    float sg   = 1.0f / (1.0f + expf(-t));
    float v    = 0.3f * xf + 3.5f * (sg + diff);
    v = fminf(fmaxf(v, 0.0f), 1.0f);
    return 1.0f - rintf(v);                     // rint = round-half-even, matches np
}

// K2: h-axis filtering + pointwise. One wave per (bi*256+wi, h-chunk).
__global__ __launch_bounds__(256) void skel_k2(const uint32_t* __restrict__ ws,
                                               float4* __restrict__ out) {
    const int ln    = threadIdx.x & 63;
    const int wid   = (blockIdx.x << 2) | (threadIdx.x >> 6);
    const int chunk = wid & (NCHUNK - 1);
    const int col   = wid >> 3;                 // bi*256 + wi
    const int wi    = col & 255, bi = col >> 8;
    const int h0    = chunk * CH;
    const uint32_t base = (uint32_t)bi * (1u << 22) + (uint32_t)wi * 64u + (uint32_t)ln;

    auto loadrow = [&](int hi) -> uint32_t {
        if (hi < 0 || hi > 255) return 0u;
        return ws[base + (uint32_t)hi * 16384u];
    };
    uint32_t q0 = loadrow(h0 - 2), q1 = loadrow(h0 - 1), q2 = loadrow(h0),
             q3 = loadrow(h0 + 1), q4 = loadrow(h0 + 2);
    for (int h = h0; h < h0 + CH; ++h) {
        uint32_t qn = loadrow(h + 3);
        uint32_t m0 = q0 & 0x7f7f7f7fu, m1 = q1 & 0x7f7f7f7fu, m2 = q2 & 0x7f7f7f7fu,
                 m3 = q3 & 0x7f7f7f7fu, m4 = q4 & 0x7f7f7f7fu;
        // 16-bit SWAR: even bytes (0,2) and odd bytes (1,3); max 729 per lane
        uint32_t e0 = m0 & 0x00ff00ffu, e1 = m1 & 0x00ff00ffu, e2 = m2 & 0x00ff00ffu,
                 e3 = m3 & 0x00ff00ffu, e4 = m4 & 0x00ff00ffu;
        uint32_t o0 = (m0 >> 8) & 0x00ff00ffu, o1 = (m1 >> 8) & 0x00ff00ffu,
                 o2 = (m2 >> 8) & 0x00ff00ffu, o3 = (m3 >> 8) & 0x00ff00ffu,
                 o4 = (m4 >> 8) & 0x00ff00ffu;
        uint32_t ae = e0 + (e1 << 1) + e2 * 3u + (e3 << 1) + e4;
        uint32_t ao = o0 + (o1 << 1) + o2 * 3u + (o3 << 1) + o4;
        if (h == 0 || h == 255) { ae -= e2; ao -= o2; }  // h-axis boundary correction
        const uint32_t xb = q2;                 // center row's x-bits (bit 7 per byte)
        float4 o;
        o.x = skel_pointwise(ae & 0xffffu, (xb >> 7)  & 1u);
        o.y = skel_pointwise(ao & 0xffffu, (xb >> 15) & 1u);
        o.z = skel_pointwise(ae >> 16,     (xb >> 23) & 1u);
        o.w = skel_pointwise(ao >> 16,     (xb >> 31) & 1u);
        out[base + (uint32_t)h * 16384u] = o;
        q0 = q1; q1 = q2; q2 = q3; q3 = q4; q4 = qn;
    }
}

extern "C" void kernel_launch(void* const* d_in, const int* in_sizes, int n_in,
                              void* d_out, int out_size, void* d_ws, size_t ws_size,
                              hipStream_t stream) {
    const float* x = (const float*)d_in[0];
    uint32_t* ws = (uint32_t*)d_ws;            // needs 32 MiB scratch
    skel_k1<<<BLOCKS, 256, 0, stream>>>(x, ws);
    skel_k2<<<BLOCKS, 256, 0, stream>>>(ws, (float4*)d_out);
}

// Round 3
// 232.252 us; speedup vs baseline: 1.1780x; 1.1780x over previous
//
#include <hip/hip_runtime.h>
#include <stdint.h>

// DifferentiableSkeletonize on (2,1,256,256,256) binary fp32 mask.
// dilated = avgpool3(avgpool3(x)) -> separable per-axis double-box:
//   interior kernel [1,2,3,2,1]/9 (zero-extended); boundary planes (i=0,255)
//   subtract one extra center tap. n = integer numerator in [0,729].
// Pointwise tail reduces EXACTLY to an integer threshold:
//   x=0: v(n=8)=0.500739 -> round 1, v(n=9)=0.493855 -> round 0
//   x=1: v >= 0.8564 always -> round 1
// => out = (x==0 && n>=9) ? 1.0f : 0.0f   (verified vs expf version, absmax 0)

typedef float  vfloat4 __attribute__((ext_vector_type(4)));  // nontemporal-compatible

#define CH 32          // outputs per wave along the marching axis
#define NCHUNK 8       // 256 / CH
#define BLOCKS 1024    // 512 slabs * 8 chunks / 4 waves-per-block

// d-axis filter: lane ln owns bytes for d = 4ln..4ln+3. b = 4 packed x-bits.
__device__ __forceinline__ uint32_t row_pack(uint32_t b, const int ln) {
    uint32_t up = (uint32_t)__shfl_up((int)b, 1);
    uint32_t dn = (uint32_t)__shfl_down((int)b, 1);
    if (ln == 0)  up = 0u;
    if (ln == 63) dn = 0u;
    uint64_t W = (uint64_t)(up >> 16) | ((uint64_t)b << 16)
               | ((uint64_t)(dn & 0xffffu) << 48);
    uint64_t S = W + ((W >> 8) << 1) + (W >> 16) * 3u + ((W >> 24) << 1) + (W >> 32);
    uint32_t n = (uint32_t)S;
    if (ln == 0)  n -= (b & 0xffu);        // d==0 boundary correction
    if (ln == 63) n -= (b & 0xff000000u);  // d==255
    return n | (b << 7);                   // x-bit -> bit7 of each byte
}

__device__ __forceinline__ uint32_t bits_of(const vfloat4 v) {
    return (v.x > 0.5f ? 0x1u : 0u) | (v.y > 0.5f ? 0x100u : 0u)
         | (v.z > 0.5f ? 0x10000u : 0u) | (v.w > 0.5f ? 0x1000000u : 0u);
}

// K1: fused d-axis + w-axis. One wave per (slab = bi*256+hi, w-chunk).
// ws byte = n_dw (<=81) | x-bit(0x80).
__global__ __launch_bounds__(256) void skel_k1(const float* __restrict__ x,
                                               uint32_t* __restrict__ ws) {
    const int ln    = threadIdx.x & 63;
    const int wid   = (blockIdx.x << 2) | (threadIdx.x >> 6);
    const int chunk = wid & (NCHUNK - 1);
    const int slab  = wid >> 3;
    const int w0    = chunk * CH;
    const vfloat4* xs = (const vfloat4*)(x + (size_t)slab * 65536);
    uint32_t* os = ws + (size_t)slab * 16384;

    auto ldraw = [&](int wi) -> vfloat4 {         // branchless, always in-bounds
        int wc = wi < 0 ? 0 : (wi > 255 ? 255 : wi);
        return __builtin_nontemporal_load(&xs[wc * 64 + ln]);
    };
    auto packb = [&](vfloat4 v, int wi) -> uint32_t {
        uint32_t b = bits_of(v);
        return (wi >= 0 && wi < 256) ? b : 0u;    // wave-uniform mask
    };

    vfloat4 a0 = ldraw(w0 - 2), a1 = ldraw(w0 - 1), a2 = ldraw(w0),
            a3 = ldraw(w0 + 1), a4 = ldraw(w0 + 2);
    vfloat4 raw0 = ldraw(w0 + 3), raw1 = ldraw(w0 + 4),
            raw2 = ldraw(w0 + 5), raw3 = ldraw(w0 + 6);
    uint32_t r0 = row_pack(packb(a0, w0 - 2), ln);
    uint32_t r1 = row_pack(packb(a1, w0 - 1), ln);
    uint32_t r2 = row_pack(packb(a2, w0    ), ln);
    uint32_t r3 = row_pack(packb(a3, w0 + 1), ln);
    uint32_t r4 = row_pack(packb(a4, w0 + 2), ln);

    for (int g = 0; g < CH; g += 4) {
        vfloat4 n0 = ldraw(w0 + g + 7),  n1 = ldraw(w0 + g + 8),
                n2 = ldraw(w0 + g + 9),  n3 = ldraw(w0 + g + 10);
        vfloat4 cur[4] = {raw0, raw1, raw2, raw3};
        #pragma unroll
        for (int j = 0; j < 4; ++j) {
            const int w = w0 + g + j;
            uint32_t rn = row_pack(packb(cur[j], w + 3), ln);
            uint32_t m0 = r0 & 0x7f7f7f7fu, m1 = r1 & 0x7f7f7f7fu,
                     m2 = r2 & 0x7f7f7f7fu, m3 = r3 & 0x7f7f7f7fu,
                     m4 = r4 & 0x7f7f7f7fu;
            uint32_t s = m0 + (m1 << 1) + m2 * 3u + (m3 << 1) + m4;  // bytes <= 81
            if (w == 0 || w == 255) s -= m2;    // w boundary correction
            s |= (r2 & 0x80808080u);            // carry center x-bits
            os[w * 64 + ln] = s;
            r0 = r1; r1 = r2; r2 = r3; r3 = r4; r4 = rn;
        }
        raw0 = n0; raw1 = n1; raw2 = n2; raw3 = n3;
    }
}

// K2: h-axis filter + integer threshold. One wave per (bi*256+wi, h-chunk).
__global__ __launch_bounds__(256) void skel_k2(const uint32_t* __restrict__ ws,
                                               vfloat4* __restrict__ out) {
    const int ln    = threadIdx.x & 63;
    const int wid   = (blockIdx.x << 2) | (threadIdx.x >> 6);
    const int chunk = wid & (NCHUNK - 1);
    const int col   = wid >> 3;
    const int wi    = col & 255, bi = col >> 8;
    const int h0    = chunk * CH;
    const uint32_t base = (uint32_t)bi * (1u << 22) + (uint32_t)wi * 64u + (uint32_t)ln;

    auto ld = [&](int hi) -> uint32_t {           // branchless clamped load
        int hc = hi < 0 ? 0 : (hi > 255 ? 255 : hi);
        return ws[base + (uint32_t)hc * 16384u];
    };
    auto msk = [&](uint32_t q, int hi) -> uint32_t {
        return (hi >= 0 && hi < 256) ? q : 0u;    // wave-uniform mask
    };

    uint32_t q0 = msk(ld(h0 - 2), h0 - 2), q1 = msk(ld(h0 - 1), h0 - 1),
             q2 = ld(h0), q3 = ld(h0 + 1), q4 = ld(h0 + 2);
    uint32_t p0 = ld(h0 + 3), p1 = ld(h0 + 4), p2 = ld(h0 + 5), p3 = ld(h0 + 6);

    for (int g = 0; g < CH; g += 4) {
        uint32_t f0 = ld(h0 + g + 7),  f1 = ld(h0 + g + 8),
                 f2 = ld(h0 + g + 9),  f3 = ld(h0 + g + 10);
        uint32_t cur[4] = {p0, p1, p2, p3};
        #pragma unroll
        for (int j = 0; j < 4; ++j) {
            const int h = h0 + g + j;
            uint32_t qn = msk(cur[j], h + 3);
            uint32_t m0 = q0 & 0x7f7f7f7fu, m1 = q1 & 0x7f7f7f7fu,
                     m2 = q2 & 0x7f7f7f7fu, m3 = q3 & 0x7f7f7f7fu,
                     m4 = q4 & 0x7f7f7f7fu;
            // 16-bit SWAR over even/odd bytes; max 729 per field
            uint32_t e0 = m0 & 0x00ff00ffu, e1 = m1 & 0x00ff00ffu,
                     e2 = m2 & 0x00ff00ffu, e3 = m3 & 0x00ff00ffu,
                     e4 = m4 & 0x00ff00ffu;
            uint32_t o0 = (m0 >> 8) & 0x00ff00ffu, o1 = (m1 >> 8) & 0x00ff00ffu,
                     o2 = (m2 >> 8) & 0x00ff00ffu, o3 = (m3 >> 8) & 0x00ff00ffu,
                     o4 = (m4 >> 8) & 0x00ff00ffu;
            uint32_t ae = e0 + (e1 << 1) + e2 * 3u + (e3 << 1) + e4;
            uint32_t ao = o0 + (o1 << 1) + o2 * 3u + (o3 << 1) + o4;
            if (h == 0 || h == 255) { ae -= e2; ao -= o2; }  // h boundary
            const uint32_t xb = q2;
            vfloat4 o;
            o.x = ((ae & 0xffffu) >= 9u && !((xb >> 7)  & 1u)) ? 1.0f : 0.0f;
            o.y = ((ao & 0xffffu) >= 9u && !((xb >> 15) & 1u)) ? 1.0f : 0.0f;
            o.z = ((ae >> 16)     >= 9u && !((xb >> 23) & 1u)) ? 1.0f : 0.0f;
            o.w = ((ao >> 16)     >= 9u && !((xb >> 31) & 1u)) ? 1.0f : 0.0f;
            __builtin_nontemporal_store(o, &out[base + (uint32_t)h * 16384u]);
            q0 = q1; q1 = q2; q2 = q3; q3 = q4; q4 = qn;
        }
        p0 = f0; p1 = f1; p2 = f2; p3 = f3;
    }
}

extern "C" void kernel_launch(void* const* d_in, const int* in_sizes, int n_in,
                              void* d_out, int out_size, void* d_ws, size_t ws_size,
                              hipStream_t stream) {
    const float* x = (const float*)d_in[0];
    uint32_t* ws = (uint32_t*)d_ws;            // needs 32 MiB scratch
    skel_k1<<<BLOCKS, 256, 0, stream>>>(x, ws);
    skel_k2<<<BLOCKS, 256, 0, stream>>>(ws, (vfloat4*)d_out);
}